// Round 16
// baseline (307.912 us; speedup 1.0000x reference)
//
#include <hip/hip_runtime.h>
#include <hip/hip_bf16.h>
#include <math.h>

#define N_NODES  50000
#define IN_DIM   128
#define HIDDEN   64
#define OUT_DIM  3
#define HEADS1   4
#define E_RAW    400000
#define E_TOT    450000   // raw edges + one self loop per node
#define NEG_SLOPE 0.2f
#define SCAN_CHUNK 1024
#define N_CHUNKS ((N_NODES + SCAN_CHUNK - 1) / SCAN_CHUNK)   // 49
#define WPREP_BLOCKS 128

typedef __attribute__((ext_vector_type(8))) short bf16x8;
typedef __attribute__((ext_vector_type(4))) float f32x4;

// bf16 bits <-> float helpers (RN pack, shift-based unpack)
static __device__ __forceinline__ float bfu(unsigned short u) {
    return __uint_as_float(((unsigned)u) << 16);
}
static __device__ __forceinline__ unsigned short f2b_bits(float v) {
    __hip_bfloat16 b = __float2bfloat16(v);
    return *reinterpret_cast<unsigned short*>(&b);
}

// ---- edge fetch, robust to int32 vs int64 storage, indices clamped ----
static __device__ __forceinline__ void get_edge(const int* __restrict__ ei, int is64,
                                                int e, int& s, int& d) {
    if (e >= E_RAW) { s = d = e - E_RAW; return; }   // self loop
    if (is64) { s = ei[2 * e]; d = ei[2 * E_RAW + 2 * e]; }
    else      { s = ei[e];     d = ei[E_RAW + e]; }
    s = min(max(s, 0), N_NODES - 1);
    d = min(max(d, 0), N_NODES - 1);
}

// Detect int64 storage: high words of int64 pairs are all 0 for values < 2^31.
__global__ void detect_int64_kernel(const int* __restrict__ ei, int* __restrict__ flag) {
    __shared__ int any_nonzero;
    if (threadIdx.x == 0) any_nonzero = 0;
    __syncthreads();
    for (int i = threadIdx.x; i < 8192; i += blockDim.x) {
        int k = i * 48;                    // 2k+1 < 786,433: in-bounds for both layouts
        if (ei[2 * k + 1] != 0) any_nonzero = 1;   // benign race
    }
    __syncthreads();
    if (threadIdx.x == 0) flag[0] = (any_nonzero == 0) ? 1 : 0;
}

// ================= fused: weight prep (blocks 0..127) + degree count (rest) =================
__global__ void wprep_count_kernel(const float* __restrict__ W1, __hip_bfloat16* __restrict__ W1T,
                                   const float* __restrict__ W2, __hip_bfloat16* __restrict__ W2T,
                                   const int* __restrict__ ei, const int* __restrict__ flag,
                                   int* __restrict__ deg) {
    int bid = blockIdx.x;
    if (bid < WPREP_BLOCKS) {
        int i = bid * 256 + threadIdx.x;       // covers 32768 = 256*128
        if (i < 256 * 128) {
            int n = i >> 7, k = i & 127;
            *((unsigned short*)W1T + i) = f2b_bits(W1[k * 256 + n]);
        }
        if (i < 64 * 256) {
            int n = i >> 8, k = i & 255;
            *((unsigned short*)W2T + i) = f2b_bits(W2[k * 64 + n]);
        }
        return;
    }
    int e = (bid - WPREP_BLOCKS) * 256 + threadIdx.x;
    if (e >= E_TOT) return;
    int s, d;
    get_edge(ei, flag[0], e, s, d);
    atomicAdd(&deg[d], 1);
}

__global__ void scan_local_kernel(const int* __restrict__ deg, int* __restrict__ row_ptr,
                                  int* __restrict__ bsums) {
    __shared__ int buf[SCAN_CHUNK];
    int base = blockIdx.x * SCAN_CHUNK;
    int i = base + threadIdx.x;
    buf[threadIdx.x] = (i < N_NODES) ? deg[i] : 0;
    __syncthreads();
    for (int off = 1; off < SCAN_CHUNK; off <<= 1) {
        int t = (threadIdx.x >= off) ? buf[threadIdx.x - off] : 0;
        __syncthreads();
        buf[threadIdx.x] += t;
        __syncthreads();
    }
    if (i < N_NODES) row_ptr[i + 1] = buf[threadIdx.x];
    if (threadIdx.x == SCAN_CHUNK - 1) bsums[blockIdx.x] = buf[SCAN_CHUNK - 1];
    if (blockIdx.x == 0 && threadIdx.x == 0) row_ptr[0] = 0;
}

__global__ void scan_bsums_kernel(int* __restrict__ bsums) {
    __shared__ int buf[64];
    int i = threadIdx.x;
    buf[i] = (i < N_CHUNKS) ? bsums[i] : 0;
    __syncthreads();
    for (int off = 1; off < 64; off <<= 1) {
        int t = (i >= off) ? buf[i - off] : 0;
        __syncthreads();
        buf[i] += t;
        __syncthreads();
    }
    if (i < N_CHUNKS) bsums[i] = (i == 0) ? 0 : buf[i - 1];
}

__global__ void scan_add_kernel(int* __restrict__ row_ptr, const int* __restrict__ bsums,
                                const int* __restrict__ deg, int* __restrict__ cursor) {
    int i = blockIdx.x * blockDim.x + threadIdx.x;
    if (i < N_NODES) {
        int incl = row_ptr[i + 1] + bsums[i / SCAN_CHUNK];
        row_ptr[i + 1] = incl;
        cursor[i] = incl - deg[i];
    }
}

__global__ void scatter_kernel(const int* __restrict__ ei, const int* __restrict__ flag,
                               int* __restrict__ cursor, int* __restrict__ csr_src) {
    int e = blockIdx.x * blockDim.x + threadIdx.x;
    if (e >= E_TOT) return;
    int s, d;
    get_edge(ei, flag[0], e, s, d);
    int pos = atomicAdd(&cursor[d], 1);
    csr_src[pos] = s;
}

// ========== layer-1 GEMM via MFMA + fused attn scores ==========
__global__ void __launch_bounds__(256) gemm_l1_mfma_kernel(
        const float* __restrict__ x, const __hip_bfloat16* __restrict__ W1T,
        const float* __restrict__ att_s, const float* __restrict__ att_d,
        __hip_bfloat16* __restrict__ h1,
        float* __restrict__ asb4, float* __restrict__ adb4) {
    __shared__ unsigned short As[16][136];
    const int tid = threadIdx.x;
    const int wave = tid >> 6, lane = tid & 63;
    const int quad = lane >> 4, m = lane & 15;
    const int row0 = blockIdx.x * 16;        // 50000/16 = 3125 exact
    {
        int r = tid >> 4, seg = tid & 15;
        const float* xa = x + (size_t)(row0 + r) * IN_DIM + seg * 8;
        float4 u = *(const float4*)xa;
        float4 v = *(const float4*)(xa + 4);
        ushort4 p0, p1;
        p0.x = f2b_bits(u.x); p0.y = f2b_bits(u.y); p0.z = f2b_bits(u.z); p0.w = f2b_bits(u.w);
        p1.x = f2b_bits(v.x); p1.y = f2b_bits(v.y); p1.z = f2b_bits(v.z); p1.w = f2b_bits(v.w);
        *(ushort4*)&As[r][seg * 8]     = p0;
        *(ushort4*)&As[r][seg * 8 + 4] = p1;
    }
    __syncthreads();
    const int n0w = wave * 64;
    f32x4 acc0 = {0.f, 0.f, 0.f, 0.f}, acc1 = acc0, acc2 = acc0, acc3 = acc0;
    #pragma unroll
    for (int k0 = 0; k0 < IN_DIM; k0 += 32) {
        int kk = k0 + quad * 8;
        bf16x8 a = *(const bf16x8*)&As[m][kk];
        bf16x8 b0 = *(const bf16x8*)(W1T + (size_t)(n0w +  0 + m) * IN_DIM + kk);
        bf16x8 b1 = *(const bf16x8*)(W1T + (size_t)(n0w + 16 + m) * IN_DIM + kk);
        bf16x8 b2 = *(const bf16x8*)(W1T + (size_t)(n0w + 32 + m) * IN_DIM + kk);
        bf16x8 b3 = *(const bf16x8*)(W1T + (size_t)(n0w + 48 + m) * IN_DIM + kk);
        acc0 = __builtin_amdgcn_mfma_f32_16x16x32_bf16(a, b0, acc0, 0, 0, 0);
        acc1 = __builtin_amdgcn_mfma_f32_16x16x32_bf16(a, b1, acc1, 0, 0, 0);
        acc2 = __builtin_amdgcn_mfma_f32_16x16x32_bf16(a, b2, acc2, 0, 0, 0);
        acc3 = __builtin_amdgcn_mfma_f32_16x16x32_bf16(a, b3, acc3, 0, 0, 0);
    }
    float ats0 = att_s[n0w +  0 + m], atd0 = att_d[n0w +  0 + m];
    float ats1 = att_s[n0w + 16 + m], atd1 = att_d[n0w + 16 + m];
    float ats2 = att_s[n0w + 32 + m], atd2 = att_d[n0w + 32 + m];
    float ats3 = att_s[n0w + 48 + m], atd3 = att_d[n0w + 48 + m];
    unsigned short* out = (unsigned short*)h1;
    #pragma unroll
    for (int i = 0; i < 4; i++) {
        int grow = row0 + quad * 4 + i;
        size_t base = (size_t)grow * 256;
        out[base + n0w +  0 + m] = f2b_bits(acc0[i]);
        out[base + n0w + 16 + m] = f2b_bits(acc1[i]);
        out[base + n0w + 32 + m] = f2b_bits(acc2[i]);
        out[base + n0w + 48 + m] = f2b_bits(acc3[i]);
        float ps = acc0[i] * ats0 + acc1[i] * ats1 + acc2[i] * ats2 + acc3[i] * ats3;
        float pd = acc0[i] * atd0 + acc1[i] * atd1 + acc2[i] * atd2 + acc3[i] * atd3;
        #pragma unroll
        for (int off = 1; off < 16; off <<= 1) {
            ps += __shfl_xor(ps, off, 16);
            pd += __shfl_xor(pd, off, 16);
        }
        if (m == 0) {
            asb4[grow * 4 + wave] = ps;
            adb4[grow * 4 + wave] = pd;
        }
    }
}

// ========== layer-2 GEMM via MFMA + fused single-head attn scores ==========
// wave w: rows row0..+15, cols w*16..+15; attn partials combined across waves via LDS.
__global__ void __launch_bounds__(256) gemm_l2_mfma_kernel(
        const __hip_bfloat16* __restrict__ eluagg, const __hip_bfloat16* __restrict__ W2T,
        const float* __restrict__ att_s, const float* __restrict__ att_d,
        __hip_bfloat16* __restrict__ h2,
        float* __restrict__ asb, float* __restrict__ adb) {
    __shared__ float sPS[4][16];
    __shared__ float sPD[4][16];
    const int tid = threadIdx.x;
    const int wave = tid >> 6, lane = tid & 63;
    const int quad = lane >> 4, m = lane & 15;
    const int row0 = blockIdx.x * 16;
    const int n0 = wave * 16;
    f32x4 acc = {0.f, 0.f, 0.f, 0.f};
    #pragma unroll
    for (int k0 = 0; k0 < 256; k0 += 32) {
        int kk = k0 + quad * 8;
        bf16x8 a = *(const bf16x8*)(eluagg + (size_t)(row0 + m) * 256 + kk);
        bf16x8 b = *(const bf16x8*)(W2T + (size_t)(n0 + m) * 256 + kk);
        acc = __builtin_amdgcn_mfma_f32_16x16x32_bf16(a, b, acc, 0, 0, 0);
    }
    float ats = att_s[n0 + m], atd = att_d[n0 + m];
    unsigned short* out = (unsigned short*)h2;
    #pragma unroll
    for (int i = 0; i < 4; i++) {
        int grow = row0 + quad * 4 + i;
        out[(size_t)grow * 64 + n0 + m] = f2b_bits(acc[i]);
        float ps = acc[i] * ats;
        float pd = acc[i] * atd;
        #pragma unroll
        for (int off = 1; off < 16; off <<= 1) {
            ps += __shfl_xor(ps, off, 16);
            pd += __shfl_xor(pd, off, 16);
        }
        if (m == 0) {
            sPS[wave][quad * 4 + i] = ps;
            sPD[wave][quad * 4 + i] = pd;
        }
    }
    __syncthreads();
    if (tid < 16) {
        float ps = sPS[0][tid] + sPS[1][tid] + sPS[2][tid] + sPS[3][tid];
        float pd = sPD[0][tid] + sPD[1][tid] + sPD[2][tid] + sPD[3][tid];
        asb[row0 + tid] = ps;
        adb[row0 + tid] = pd;
    }
}

// ========== softmax stats, 4 heads, single pass (shift-invariant; scores O(10)) ==========
__global__ void softmax_stats4_kernel(const int* __restrict__ row_ptr,
                                      const int* __restrict__ csr_src,
                                      const float* __restrict__ asb4,
                                      const float* __restrict__ adb4,
                                      float* __restrict__ wT,       // [4,E]
                                      float* __restrict__ inv_l) {
    int n = blockIdx.x * blockDim.x + threadIdx.x;
    if (n >= N_NODES) return;
    int b = row_ptr[n], e = row_ptr[n + 1];
    float4 adn = ((const float4*)adb4)[n];
    float4 l = make_float4(0.f, 0.f, 0.f, 0.f);
    for (int j = b; j < e; j++) {
        int s = csr_src[j];
        float4 v = ((const float4*)asb4)[s];
        v.x += adn.x; v.y += adn.y; v.z += adn.z; v.w += adn.w;
        v.x = (v.x > 0.f) ? v.x : NEG_SLOPE * v.x;
        v.y = (v.y > 0.f) ? v.y : NEG_SLOPE * v.y;
        v.z = (v.z > 0.f) ? v.z : NEG_SLOPE * v.z;
        v.w = (v.w > 0.f) ? v.w : NEG_SLOPE * v.w;
        float4 p;
        p.x = __expf(v.x); p.y = __expf(v.y); p.z = __expf(v.z); p.w = __expf(v.w);
        wT[0 * E_TOT + j] = p.x;
        wT[1 * E_TOT + j] = p.y;
        wT[2 * E_TOT + j] = p.z;
        wT[3 * E_TOT + j] = p.w;
        l.x += p.x; l.y += p.y; l.z += p.z; l.w += p.w;
    }
    float4 il;
    il.x = 1.f / (l.x + 1e-16f); il.y = 1.f / (l.y + 1e-16f);
    il.z = 1.f / (l.z + 1e-16f); il.w = 1.f / (l.w + 1e-16f);
    ((float4*)inv_l)[n] = il;
}

// ---- single-head stats (layer 2), single pass ----
__global__ void softmax_stats1_kernel(const int* __restrict__ row_ptr,
                                      const int* __restrict__ csr_src,
                                      const float* __restrict__ as_,
                                      const float* __restrict__ ad_,
                                      float* __restrict__ wT,
                                      float* __restrict__ inv_l) {
    int n = blockIdx.x * blockDim.x + threadIdx.x;
    if (n >= N_NODES) return;
    int b = row_ptr[n], e = row_ptr[n + 1];
    float adn = ad_[n];
    float l = 0.f;
    for (int j = b; j < e; j++) {
        float v = as_[csr_src[j]] + adn;
        v = (v > 0.f) ? v : NEG_SLOPE * v;
        float p = __expf(v);
        wT[j] = p;
        l += p;
    }
    inv_l[n] = 1.f / (l + 1e-16f);
}

// ========== gather4 + bias + elu, writes bf16 eluagg [N,256]; unroll x8 ==========
__global__ void __launch_bounds__(256) gat_gather4_kernel(
        const int* __restrict__ row_ptr, const int* __restrict__ csr_src,
        const float* __restrict__ wT, const float* __restrict__ inv_l,
        const __hip_bfloat16* __restrict__ h1, const float* __restrict__ bias,
        __hip_bfloat16* __restrict__ eluagg) {
    int wave = threadIdx.x >> 6;
    int lane = threadIdx.x & 63;
    int n = blockIdx.x * 4 + wave;
    if (n >= N_NODES) return;
    int b = row_ptr[n], e = row_ptr[n + 1];
    int head = lane >> 4;
    const float* wTh = wT + (size_t)head * E_TOT;
    float4 a0 = make_float4(0, 0, 0, 0), a1 = a0, a2 = a0, a3 = a0;
    int j = b;
    for (; j + 8 <= e; j += 8) {
        int s0 = csr_src[j],     s1 = csr_src[j + 1], s2 = csr_src[j + 2], s3 = csr_src[j + 3];
        int s4 = csr_src[j + 4], s5 = csr_src[j + 5], s6 = csr_src[j + 6], s7 = csr_src[j + 7];
        float w0 = wTh[j],     w1 = wTh[j + 1], w2 = wTh[j + 2], w3 = wTh[j + 3];
        float w4 = wTh[j + 4], w5 = wTh[j + 5], w6 = wTh[j + 6], w7 = wTh[j + 7];
        ushort4 f0 = *(const ushort4*)(h1 + (size_t)s0 * 256 + lane * 4);
        ushort4 f1 = *(const ushort4*)(h1 + (size_t)s1 * 256 + lane * 4);
        ushort4 f2 = *(const ushort4*)(h1 + (size_t)s2 * 256 + lane * 4);
        ushort4 f3 = *(const ushort4*)(h1 + (size_t)s3 * 256 + lane * 4);
        ushort4 f4 = *(const ushort4*)(h1 + (size_t)s4 * 256 + lane * 4);
        ushort4 f5 = *(const ushort4*)(h1 + (size_t)s5 * 256 + lane * 4);
        ushort4 f6 = *(const ushort4*)(h1 + (size_t)s6 * 256 + lane * 4);
        ushort4 f7 = *(const ushort4*)(h1 + (size_t)s7 * 256 + lane * 4);
        a0.x += w0 * bfu(f0.x); a0.y += w0 * bfu(f0.y); a0.z += w0 * bfu(f0.z); a0.w += w0 * bfu(f0.w);
        a1.x += w1 * bfu(f1.x); a1.y += w1 * bfu(f1.y); a1.z += w1 * bfu(f1.z); a1.w += w1 * bfu(f1.w);
        a2.x += w2 * bfu(f2.x); a2.y += w2 * bfu(f2.y); a2.z += w2 * bfu(f2.z); a2.w += w2 * bfu(f2.w);
        a3.x += w3 * bfu(f3.x); a3.y += w3 * bfu(f3.y); a3.z += w3 * bfu(f3.z); a3.w += w3 * bfu(f3.w);
        a0.x += w4 * bfu(f4.x); a0.y += w4 * bfu(f4.y); a0.z += w4 * bfu(f4.z); a0.w += w4 * bfu(f4.w);
        a1.x += w5 * bfu(f5.x); a1.y += w5 * bfu(f5.y); a1.z += w5 * bfu(f5.z); a1.w += w5 * bfu(f5.w);
        a2.x += w6 * bfu(f6.x); a2.y += w6 * bfu(f6.y); a2.z += w6 * bfu(f6.z); a2.w += w6 * bfu(f6.w);
        a3.x += w7 * bfu(f7.x); a3.y += w7 * bfu(f7.y); a3.z += w7 * bfu(f7.z); a3.w += w7 * bfu(f7.w);
    }
    for (; j < e; j++) {
        int s = csr_src[j];
        float w = wTh[j];
        ushort4 f = *(const ushort4*)(h1 + (size_t)s * 256 + lane * 4);
        a0.x += w * bfu(f.x); a0.y += w * bfu(f.y); a0.z += w * bfu(f.z); a0.w += w * bfu(f.w);
    }
    float il = inv_l[n * 4 + head];
    float4 bb = *(const float4*)(bias + lane * 4);
    float4 r;
    r.x = (a0.x + a1.x + a2.x + a3.x) * il + bb.x;
    r.y = (a0.y + a1.y + a2.y + a3.y) * il + bb.y;
    r.z = (a0.z + a1.z + a2.z + a3.z) * il + bb.z;
    r.w = (a0.w + a1.w + a2.w + a3.w) * il + bb.w;
    r.x = (r.x > 0.f) ? r.x : expm1f(r.x);
    r.y = (r.y > 0.f) ? r.y : expm1f(r.y);
    r.z = (r.z > 0.f) ? r.z : expm1f(r.z);
    r.w = (r.w > 0.f) ? r.w : expm1f(r.w);
    ushort4 st;
    st.x = f2b_bits(r.x); st.y = f2b_bits(r.y); st.z = f2b_bits(r.z); st.w = f2b_bits(r.w);
    *(ushort4*)(eluagg + (size_t)n * 256 + lane * 4) = st;
}

// ========== gather1 + elu + output projection, fully fused; h2 is bf16 ==========
__global__ void __launch_bounds__(256) gat_gather1_out_kernel(
        const int* __restrict__ row_ptr, const int* __restrict__ csr_src,
        const float* __restrict__ wT, const float* __restrict__ inv_l,
        const __hip_bfloat16* __restrict__ h2, const float* __restrict__ bias,
        const float* __restrict__ Wout, const float* __restrict__ bout,
        float* __restrict__ out) {
    int wave = threadIdx.x >> 6;
    int lane = threadIdx.x & 63;
    int n = blockIdx.x * 4 + wave;
    if (n >= N_NODES) return;
    int b = row_ptr[n], e = row_ptr[n + 1];
    int cg = lane & 15, slot = lane >> 4;
    float4 acc = make_float4(0, 0, 0, 0);
    for (int j0 = b; j0 < e; j0 += 4) {
        int j = j0 + slot;
        float w = 0.f; int s = 0;
        if (j < e) { s = csr_src[j]; w = wT[j]; }
        ushort4 f = *(const ushort4*)(h2 + (size_t)s * 64 + cg * 4);
        acc.x += w * bfu(f.x); acc.y += w * bfu(f.y);
        acc.z += w * bfu(f.z); acc.w += w * bfu(f.w);
    }
    acc.x += __shfl_xor(acc.x, 16, 64); acc.y += __shfl_xor(acc.y, 16, 64);
    acc.z += __shfl_xor(acc.z, 16, 64); acc.w += __shfl_xor(acc.w, 16, 64);
    acc.x += __shfl_xor(acc.x, 32, 64); acc.y += __shfl_xor(acc.y, 32, 64);
    acc.z += __shfl_xor(acc.z, 32, 64); acc.w += __shfl_xor(acc.w, 32, 64);
    float il = inv_l[n];
    float4 bb = *(const float4*)(bias + cg * 4);
    float4 v;
    v.x = acc.x * il + bb.x; v.y = acc.y * il + bb.y;
    v.z = acc.z * il + bb.z; v.w = acc.w * il + bb.w;
    v.x = (v.x > 0.f) ? v.x : expm1f(v.x);
    v.y = (v.y > 0.f) ? v.y : expm1f(v.y);
    v.z = (v.z > 0.f) ? v.z : expm1f(v.z);
    v.w = (v.w > 0.f) ? v.w : expm1f(v.w);
    int c0 = cg * 4;
    float o0 = v.x * Wout[(c0+0)*OUT_DIM+0] + v.y * Wout[(c0+1)*OUT_DIM+0]
             + v.z * Wout[(c0+2)*OUT_DIM+0] + v.w * Wout[(c0+3)*OUT_DIM+0];
    float o1 = v.x * Wout[(c0+0)*OUT_DIM+1] + v.y * Wout[(c0+1)*OUT_DIM+1]
             + v.z * Wout[(c0+2)*OUT_DIM+1] + v.w * Wout[(c0+3)*OUT_DIM+1];
    float o2 = v.x * Wout[(c0+0)*OUT_DIM+2] + v.y * Wout[(c0+1)*OUT_DIM+2]
             + v.z * Wout[(c0+2)*OUT_DIM+2] + v.w * Wout[(c0+3)*OUT_DIM+2];
    #pragma unroll
    for (int off = 1; off < 16; off <<= 1) {
        o0 += __shfl_xor(o0, off, 64);
        o1 += __shfl_xor(o1, off, 64);
        o2 += __shfl_xor(o2, off, 64);
    }
    if (lane == 0) {
        out[n * OUT_DIM + 0] = o0 + bout[0];
        out[n * OUT_DIM + 1] = o1 + bout[1];
        out[n * OUT_DIM + 2] = o2 + bout[2];
    }
}

extern "C" void kernel_launch(void* const* d_in, const int* in_sizes, int n_in,
                              void* d_out, int out_size, void* d_ws, size_t ws_size,
                              hipStream_t stream) {
    const float* x    = (const float*)d_in[0];
    const int*   ei   = (const int*)d_in[1];
    const float* W1   = (const float*)d_in[2];
    const float* as1  = (const float*)d_in[3];
    const float* ad1  = (const float*)d_in[4];
    const float* b1   = (const float*)d_in[5];
    const float* W2   = (const float*)d_in[6];
    const float* as2  = (const float*)d_in[7];
    const float* ad2  = (const float*)d_in[8];
    const float* b2v  = (const float*)d_in[9];
    const float* Wout = (const float*)d_in[10];
    const float* bout = (const float*)d_in[11];
    float* out = (float*)d_out;

    // ---- workspace layout (~70 MB), flag at base ----
    float* ws    = (float*)d_ws;
    int*   flag  = (int*)ws;                          // 16 floats reserved
    float* asb4  = ws + 16;                           // [N,4]
    float* adb4  = asb4 + (size_t)N_NODES * 4;        // [N,4]
    float* ilb4  = adb4 + (size_t)N_NODES * 4;        // [N,4]
    float* asb1  = ilb4 + (size_t)N_NODES * 4;        // [N]
    float* adb1  = asb1 + N_NODES;                    // [N]
    float* ilb1  = adb1 + N_NODES;                    // [N]
    float* wT    = ilb1 + N_NODES;                    // [4,E]
    __hip_bfloat16* h1     = (__hip_bfloat16*)(wT + (size_t)E_TOT * 4);       // [N,256] bf16
    __hip_bfloat16* eluagg = (__hip_bfloat16*)(h1 + (size_t)N_NODES * 256);   // [N,256] bf16
    __hip_bfloat16* h2     = (__hip_bfloat16*)(eluagg + (size_t)N_NODES * 256); // [N,64] bf16
    __hip_bfloat16* W1T    = (__hip_bfloat16*)(h2 + (size_t)N_NODES * 64);    // [256,128] bf16
    __hip_bfloat16* W2T    = W1T + 256 * 128;                                  // [64,256] bf16
    int* deg     = (int*)(W2T + 64 * 256);            // [N]
    int* bsums   = deg + N_NODES;                     // 64
    int* row_ptr = bsums + 64;                        // [N+1] (+pad)
    int* cursor  = row_ptr + N_NODES + 16;            // [N]
    int* csr_src = cursor + N_NODES;                  // [E]

    const int EB = (E_TOT + 255) / 256;
    const int NB = (N_NODES + 255) / 256;
    const int AB = (N_NODES + 3) / 4;
    const int MB = N_NODES / 16;                      // 3125 MFMA row-blocks

    detect_int64_kernel<<<1, 256, 0, stream>>>(ei, flag);
    hipMemsetAsync(deg, 0, (size_t)N_NODES * sizeof(int), stream);

    // ---- fused weight-prep + degree count; then scan chain; then scatter ----
    wprep_count_kernel<<<WPREP_BLOCKS + EB, 256, 0, stream>>>(W1, W1T, W2, W2T, ei, flag, deg);
    scan_local_kernel<<<N_CHUNKS, SCAN_CHUNK, 0, stream>>>(deg, row_ptr, bsums);
    scan_bsums_kernel<<<1, 64, 0, stream>>>(bsums);
    scan_add_kernel<<<NB, 256, 0, stream>>>(row_ptr, bsums, deg, cursor);
    scatter_kernel<<<EB, 256, 0, stream>>>(ei, flag, cursor, csr_src);

    // ===== layer 1: MFMA GEMM (+attn fused) + stats + gather(+bias+elu -> bf16) =====
    gemm_l1_mfma_kernel<<<MB, 256, 0, stream>>>(x, W1T, as1, ad1, h1, asb4, adb4);
    softmax_stats4_kernel<<<NB, 256, 0, stream>>>(row_ptr, csr_src, asb4, adb4, wT, ilb4);
    gat_gather4_kernel<<<AB, 256, 0, stream>>>(row_ptr, csr_src, wT, ilb4, h1, b1, eluagg);

    // ===== layer 2: MFMA GEMM (+attn fused) + stats =====
    gemm_l2_mfma_kernel<<<MB, 256, 0, stream>>>(eluagg, W2T, as2, ad2, h2, asb1, adb1);
    softmax_stats1_kernel<<<NB, 256, 0, stream>>>(row_ptr, csr_src, asb1, adb1, wT, ilb1);

    // ===== fused gather + elu + output projection =====
    gat_gather1_out_kernel<<<AB, 256, 0, stream>>>(row_ptr, csr_src, wT, ilb1, h2,
                                                   b2v, Wout, bout, out);
}

// Round 17
// 296.627 us; speedup vs baseline: 1.0380x; 1.0380x over previous
//
#include <hip/hip_runtime.h>
#include <hip/hip_bf16.h>
#include <math.h>

#define N_NODES  50000
#define IN_DIM   128
#define HIDDEN   64
#define OUT_DIM  3
#define HEADS1   4
#define E_RAW    400000
#define E_TOT    450000   // raw edges + one self loop per node
#define NEG_SLOPE 0.2f
#define SCAN_CHUNK 1024
#define N_CHUNKS ((N_NODES + SCAN_CHUNK - 1) / SCAN_CHUNK)   // 49
#define WPREP_BLOCKS 128

typedef __attribute__((ext_vector_type(8))) short bf16x8;
typedef __attribute__((ext_vector_type(4))) float f32x4;

// bf16 bits <-> float helpers (RN pack, shift-based unpack)
static __device__ __forceinline__ float bfu(unsigned short u) {
    return __uint_as_float(((unsigned)u) << 16);
}
static __device__ __forceinline__ unsigned short f2b_bits(float v) {
    __hip_bfloat16 b = __float2bfloat16(v);
    return *reinterpret_cast<unsigned short*>(&b);
}

// ---- edge fetch, robust to int32 vs int64 storage, indices clamped ----
static __device__ __forceinline__ void get_edge(const int* __restrict__ ei, int is64,
                                                int e, int& s, int& d) {
    if (e >= E_RAW) { s = d = e - E_RAW; return; }   // self loop
    if (is64) { s = ei[2 * e]; d = ei[2 * E_RAW + 2 * e]; }
    else      { s = ei[e];     d = ei[E_RAW + e]; }
    s = min(max(s, 0), N_NODES - 1);
    d = min(max(d, 0), N_NODES - 1);
}

// Detect int64 storage: high words of int64 pairs are all 0 for values < 2^31.
__global__ void detect_int64_kernel(const int* __restrict__ ei, int* __restrict__ flag) {
    __shared__ int any_nonzero;
    if (threadIdx.x == 0) any_nonzero = 0;
    __syncthreads();
    for (int i = threadIdx.x; i < 8192; i += blockDim.x) {
        int k = i * 48;                    // 2k+1 < 786,433: in-bounds for both layouts
        if (ei[2 * k + 1] != 0) any_nonzero = 1;   // benign race
    }
    __syncthreads();
    if (threadIdx.x == 0) flag[0] = (any_nonzero == 0) ? 1 : 0;
}

// ================= fused: weight prep (blocks 0..127) + degree count (rest) =================
__global__ void wprep_count_kernel(const float* __restrict__ W1, __hip_bfloat16* __restrict__ W1T,
                                   const float* __restrict__ W2, __hip_bfloat16* __restrict__ W2T,
                                   const int* __restrict__ ei, const int* __restrict__ flag,
                                   int* __restrict__ deg) {
    int bid = blockIdx.x;
    if (bid < WPREP_BLOCKS) {
        int i = bid * 256 + threadIdx.x;       // covers 32768 = 256*128
        if (i < 256 * 128) {
            int n = i >> 7, k = i & 127;
            *((unsigned short*)W1T + i) = f2b_bits(W1[k * 256 + n]);
        }
        if (i < 64 * 256) {
            int n = i >> 8, k = i & 255;
            *((unsigned short*)W2T + i) = f2b_bits(W2[k * 64 + n]);
        }
        return;
    }
    int e = (bid - WPREP_BLOCKS) * 256 + threadIdx.x;
    if (e >= E_TOT) return;
    int s, d;
    get_edge(ei, flag[0], e, s, d);
    atomicAdd(&deg[d], 1);
}

__global__ void scan_local_kernel(const int* __restrict__ deg, int* __restrict__ row_ptr,
                                  int* __restrict__ bsums) {
    __shared__ int buf[SCAN_CHUNK];
    int base = blockIdx.x * SCAN_CHUNK;
    int i = base + threadIdx.x;
    buf[threadIdx.x] = (i < N_NODES) ? deg[i] : 0;
    __syncthreads();
    for (int off = 1; off < SCAN_CHUNK; off <<= 1) {
        int t = (threadIdx.x >= off) ? buf[threadIdx.x - off] : 0;
        __syncthreads();
        buf[threadIdx.x] += t;
        __syncthreads();
    }
    if (i < N_NODES) row_ptr[i + 1] = buf[threadIdx.x];
    if (threadIdx.x == SCAN_CHUNK - 1) bsums[blockIdx.x] = buf[SCAN_CHUNK - 1];
    if (blockIdx.x == 0 && threadIdx.x == 0) row_ptr[0] = 0;
}

__global__ void scan_bsums_kernel(int* __restrict__ bsums) {
    __shared__ int buf[64];
    int i = threadIdx.x;
    buf[i] = (i < N_CHUNKS) ? bsums[i] : 0;
    __syncthreads();
    for (int off = 1; off < 64; off <<= 1) {
        int t = (i >= off) ? buf[i - off] : 0;
        __syncthreads();
        buf[i] += t;
        __syncthreads();
    }
    if (i < N_CHUNKS) bsums[i] = (i == 0) ? 0 : buf[i - 1];
}

__global__ void scan_add_kernel(int* __restrict__ row_ptr, const int* __restrict__ bsums,
                                const int* __restrict__ deg, int* __restrict__ cursor) {
    int i = blockIdx.x * blockDim.x + threadIdx.x;
    if (i < N_NODES) {
        int incl = row_ptr[i + 1] + bsums[i / SCAN_CHUNK];
        row_ptr[i + 1] = incl;
        cursor[i] = incl - deg[i];
    }
}

__global__ void scatter_kernel(const int* __restrict__ ei, const int* __restrict__ flag,
                               int* __restrict__ cursor, int* __restrict__ csr_src) {
    int e = blockIdx.x * blockDim.x + threadIdx.x;
    if (e >= E_TOT) return;
    int s, d;
    get_edge(ei, flag[0], e, s, d);
    int pos = atomicAdd(&cursor[d], 1);
    csr_src[pos] = s;
}

// ========== layer-1 GEMM via MFMA + fused attn scores ==========
__global__ void __launch_bounds__(256) gemm_l1_mfma_kernel(
        const float* __restrict__ x, const __hip_bfloat16* __restrict__ W1T,
        const float* __restrict__ att_s, const float* __restrict__ att_d,
        __hip_bfloat16* __restrict__ h1,
        float* __restrict__ asb4, float* __restrict__ adb4) {
    __shared__ unsigned short As[16][136];
    const int tid = threadIdx.x;
    const int wave = tid >> 6, lane = tid & 63;
    const int quad = lane >> 4, m = lane & 15;
    const int row0 = blockIdx.x * 16;        // 50000/16 = 3125 exact
    {
        int r = tid >> 4, seg = tid & 15;
        const float* xa = x + (size_t)(row0 + r) * IN_DIM + seg * 8;
        float4 u = *(const float4*)xa;
        float4 v = *(const float4*)(xa + 4);
        ushort4 p0, p1;
        p0.x = f2b_bits(u.x); p0.y = f2b_bits(u.y); p0.z = f2b_bits(u.z); p0.w = f2b_bits(u.w);
        p1.x = f2b_bits(v.x); p1.y = f2b_bits(v.y); p1.z = f2b_bits(v.z); p1.w = f2b_bits(v.w);
        *(ushort4*)&As[r][seg * 8]     = p0;
        *(ushort4*)&As[r][seg * 8 + 4] = p1;
    }
    __syncthreads();
    const int n0w = wave * 64;
    f32x4 acc0 = {0.f, 0.f, 0.f, 0.f}, acc1 = acc0, acc2 = acc0, acc3 = acc0;
    #pragma unroll
    for (int k0 = 0; k0 < IN_DIM; k0 += 32) {
        int kk = k0 + quad * 8;
        bf16x8 a = *(const bf16x8*)&As[m][kk];
        bf16x8 b0 = *(const bf16x8*)(W1T + (size_t)(n0w +  0 + m) * IN_DIM + kk);
        bf16x8 b1 = *(const bf16x8*)(W1T + (size_t)(n0w + 16 + m) * IN_DIM + kk);
        bf16x8 b2 = *(const bf16x8*)(W1T + (size_t)(n0w + 32 + m) * IN_DIM + kk);
        bf16x8 b3 = *(const bf16x8*)(W1T + (size_t)(n0w + 48 + m) * IN_DIM + kk);
        acc0 = __builtin_amdgcn_mfma_f32_16x16x32_bf16(a, b0, acc0, 0, 0, 0);
        acc1 = __builtin_amdgcn_mfma_f32_16x16x32_bf16(a, b1, acc1, 0, 0, 0);
        acc2 = __builtin_amdgcn_mfma_f32_16x16x32_bf16(a, b2, acc2, 0, 0, 0);
        acc3 = __builtin_amdgcn_mfma_f32_16x16x32_bf16(a, b3, acc3, 0, 0, 0);
    }
    float ats0 = att_s[n0w +  0 + m], atd0 = att_d[n0w +  0 + m];
    float ats1 = att_s[n0w + 16 + m], atd1 = att_d[n0w + 16 + m];
    float ats2 = att_s[n0w + 32 + m], atd2 = att_d[n0w + 32 + m];
    float ats3 = att_s[n0w + 48 + m], atd3 = att_d[n0w + 48 + m];
    unsigned short* out = (unsigned short*)h1;
    #pragma unroll
    for (int i = 0; i < 4; i++) {
        int grow = row0 + quad * 4 + i;
        size_t base = (size_t)grow * 256;
        out[base + n0w +  0 + m] = f2b_bits(acc0[i]);
        out[base + n0w + 16 + m] = f2b_bits(acc1[i]);
        out[base + n0w + 32 + m] = f2b_bits(acc2[i]);
        out[base + n0w + 48 + m] = f2b_bits(acc3[i]);
        float ps = acc0[i] * ats0 + acc1[i] * ats1 + acc2[i] * ats2 + acc3[i] * ats3;
        float pd = acc0[i] * atd0 + acc1[i] * atd1 + acc2[i] * atd2 + acc3[i] * atd3;
        #pragma unroll
        for (int off = 1; off < 16; off <<= 1) {
            ps += __shfl_xor(ps, off, 16);
            pd += __shfl_xor(pd, off, 16);
        }
        if (m == 0) {
            asb4[grow * 4 + wave] = ps;
            adb4[grow * 4 + wave] = pd;
        }
    }
}

// ========== layer-2 GEMM via MFMA + fused single-head attn scores ==========
__global__ void __launch_bounds__(256) gemm_l2_mfma_kernel(
        const __hip_bfloat16* __restrict__ eluagg, const __hip_bfloat16* __restrict__ W2T,
        const float* __restrict__ att_s, const float* __restrict__ att_d,
        __hip_bfloat16* __restrict__ h2,
        float* __restrict__ asb, float* __restrict__ adb) {
    __shared__ float sPS[4][16];
    __shared__ float sPD[4][16];
    const int tid = threadIdx.x;
    const int wave = tid >> 6, lane = tid & 63;
    const int quad = lane >> 4, m = lane & 15;
    const int row0 = blockIdx.x * 16;
    const int n0 = wave * 16;
    f32x4 acc = {0.f, 0.f, 0.f, 0.f};
    #pragma unroll
    for (int k0 = 0; k0 < 256; k0 += 32) {
        int kk = k0 + quad * 8;
        bf16x8 a = *(const bf16x8*)(eluagg + (size_t)(row0 + m) * 256 + kk);
        bf16x8 b = *(const bf16x8*)(W2T + (size_t)(n0 + m) * 256 + kk);
        acc = __builtin_amdgcn_mfma_f32_16x16x32_bf16(a, b, acc, 0, 0, 0);
    }
    float ats = att_s[n0 + m], atd = att_d[n0 + m];
    unsigned short* out = (unsigned short*)h2;
    #pragma unroll
    for (int i = 0; i < 4; i++) {
        int grow = row0 + quad * 4 + i;
        out[(size_t)grow * 64 + n0 + m] = f2b_bits(acc[i]);
        float ps = acc[i] * ats;
        float pd = acc[i] * atd;
        #pragma unroll
        for (int off = 1; off < 16; off <<= 1) {
            ps += __shfl_xor(ps, off, 16);
            pd += __shfl_xor(pd, off, 16);
        }
        if (m == 0) {
            sPS[wave][quad * 4 + i] = ps;
            sPD[wave][quad * 4 + i] = pd;
        }
    }
    __syncthreads();
    if (tid < 16) {
        float ps = sPS[0][tid] + sPS[1][tid] + sPS[2][tid] + sPS[3][tid];
        float pd = sPD[0][tid] + sPD[1][tid] + sPD[2][tid] + sPD[3][tid];
        asb[row0 + tid] = ps;
        adb[row0 + tid] = pd;
    }
}

// ========== softmax stats, 4 heads, single pass (shift-invariant; scores O(10)) ==========
__global__ void softmax_stats4_kernel(const int* __restrict__ row_ptr,
                                      const int* __restrict__ csr_src,
                                      const float* __restrict__ asb4,
                                      const float* __restrict__ adb4,
                                      float* __restrict__ wT,       // [4,E]
                                      float* __restrict__ inv_l) {
    int n = blockIdx.x * blockDim.x + threadIdx.x;
    if (n >= N_NODES) return;
    int b = row_ptr[n], e = row_ptr[n + 1];
    float4 adn = ((const float4*)adb4)[n];
    float4 l = make_float4(0.f, 0.f, 0.f, 0.f);
    for (int j = b; j < e; j++) {
        int s = csr_src[j];
        float4 v = ((const float4*)asb4)[s];
        v.x += adn.x; v.y += adn.y; v.z += adn.z; v.w += adn.w;
        v.x = (v.x > 0.f) ? v.x : NEG_SLOPE * v.x;
        v.y = (v.y > 0.f) ? v.y : NEG_SLOPE * v.y;
        v.z = (v.z > 0.f) ? v.z : NEG_SLOPE * v.z;
        v.w = (v.w > 0.f) ? v.w : NEG_SLOPE * v.w;
        float4 p;
        p.x = __expf(v.x); p.y = __expf(v.y); p.z = __expf(v.z); p.w = __expf(v.w);
        wT[0 * E_TOT + j] = p.x;
        wT[1 * E_TOT + j] = p.y;
        wT[2 * E_TOT + j] = p.z;
        wT[3 * E_TOT + j] = p.w;
        l.x += p.x; l.y += p.y; l.z += p.z; l.w += p.w;
    }
    float4 il;
    il.x = 1.f / (l.x + 1e-16f); il.y = 1.f / (l.y + 1e-16f);
    il.z = 1.f / (l.z + 1e-16f); il.w = 1.f / (l.w + 1e-16f);
    ((float4*)inv_l)[n] = il;
}

// ---- single-head stats (layer 2), single pass ----
__global__ void softmax_stats1_kernel(const int* __restrict__ row_ptr,
                                      const int* __restrict__ csr_src,
                                      const float* __restrict__ as_,
                                      const float* __restrict__ ad_,
                                      float* __restrict__ wT,
                                      float* __restrict__ inv_l) {
    int n = blockIdx.x * blockDim.x + threadIdx.x;
    if (n >= N_NODES) return;
    int b = row_ptr[n], e = row_ptr[n + 1];
    float adn = ad_[n];
    float l = 0.f;
    for (int j = b; j < e; j++) {
        float v = as_[csr_src[j]] + adn;
        v = (v > 0.f) ? v : NEG_SLOPE * v;
        float p = __expf(v);
        wT[j] = p;
        l += p;
    }
    inv_l[n] = 1.f / (l + 1e-16f);
}

// ========== gather4 + bias + elu, writes bf16 eluagg [N,256]; unroll x4 (x8 regressed r16) ==========
__global__ void __launch_bounds__(256) gat_gather4_kernel(
        const int* __restrict__ row_ptr, const int* __restrict__ csr_src,
        const float* __restrict__ wT, const float* __restrict__ inv_l,
        const __hip_bfloat16* __restrict__ h1, const float* __restrict__ bias,
        __hip_bfloat16* __restrict__ eluagg) {
    int wave = threadIdx.x >> 6;
    int lane = threadIdx.x & 63;
    int n = blockIdx.x * 4 + wave;
    if (n >= N_NODES) return;
    int b = row_ptr[n], e = row_ptr[n + 1];
    int head = lane >> 4;
    const float* wTh = wT + (size_t)head * E_TOT;
    float4 a0 = make_float4(0, 0, 0, 0), a1 = a0, a2 = a0, a3 = a0;
    int j = b;
    for (; j + 4 <= e; j += 4) {
        int s0 = csr_src[j], s1 = csr_src[j + 1], s2 = csr_src[j + 2], s3 = csr_src[j + 3];
        float w0 = wTh[j], w1 = wTh[j + 1], w2 = wTh[j + 2], w3 = wTh[j + 3];
        ushort4 f0 = *(const ushort4*)(h1 + (size_t)s0 * 256 + lane * 4);
        ushort4 f1 = *(const ushort4*)(h1 + (size_t)s1 * 256 + lane * 4);
        ushort4 f2 = *(const ushort4*)(h1 + (size_t)s2 * 256 + lane * 4);
        ushort4 f3 = *(const ushort4*)(h1 + (size_t)s3 * 256 + lane * 4);
        a0.x += w0 * bfu(f0.x); a0.y += w0 * bfu(f0.y); a0.z += w0 * bfu(f0.z); a0.w += w0 * bfu(f0.w);
        a1.x += w1 * bfu(f1.x); a1.y += w1 * bfu(f1.y); a1.z += w1 * bfu(f1.z); a1.w += w1 * bfu(f1.w);
        a2.x += w2 * bfu(f2.x); a2.y += w2 * bfu(f2.y); a2.z += w2 * bfu(f2.z); a2.w += w2 * bfu(f2.w);
        a3.x += w3 * bfu(f3.x); a3.y += w3 * bfu(f3.y); a3.z += w3 * bfu(f3.z); a3.w += w3 * bfu(f3.w);
    }
    for (; j < e; j++) {
        int s = csr_src[j];
        float w = wTh[j];
        ushort4 f = *(const ushort4*)(h1 + (size_t)s * 256 + lane * 4);
        a0.x += w * bfu(f.x); a0.y += w * bfu(f.y); a0.z += w * bfu(f.z); a0.w += w * bfu(f.w);
    }
    float il = inv_l[n * 4 + head];
    float4 bb = *(const float4*)(bias + lane * 4);
    float4 r;
    r.x = (a0.x + a1.x + a2.x + a3.x) * il + bb.x;
    r.y = (a0.y + a1.y + a2.y + a3.y) * il + bb.y;
    r.z = (a0.z + a1.z + a2.z + a3.z) * il + bb.z;
    r.w = (a0.w + a1.w + a2.w + a3.w) * il + bb.w;
    r.x = (r.x > 0.f) ? r.x : expm1f(r.x);
    r.y = (r.y > 0.f) ? r.y : expm1f(r.y);
    r.z = (r.z > 0.f) ? r.z : expm1f(r.z);
    r.w = (r.w > 0.f) ? r.w : expm1f(r.w);
    ushort4 st;
    st.x = f2b_bits(r.x); st.y = f2b_bits(r.y); st.z = f2b_bits(r.z); st.w = f2b_bits(r.w);
    *(ushort4*)(eluagg + (size_t)n * 256 + lane * 4) = st;
}

// ========== gather1 + elu + output projection, fully fused; h2 is bf16 ==========
__global__ void __launch_bounds__(256) gat_gather1_out_kernel(
        const int* __restrict__ row_ptr, const int* __restrict__ csr_src,
        const float* __restrict__ wT, const float* __restrict__ inv_l,
        const __hip_bfloat16* __restrict__ h2, const float* __restrict__ bias,
        const float* __restrict__ Wout, const float* __restrict__ bout,
        float* __restrict__ out) {
    int wave = threadIdx.x >> 6;
    int lane = threadIdx.x & 63;
    int n = blockIdx.x * 4 + wave;
    if (n >= N_NODES) return;
    int b = row_ptr[n], e = row_ptr[n + 1];
    int cg = lane & 15, slot = lane >> 4;
    float4 acc = make_float4(0, 0, 0, 0);
    for (int j0 = b; j0 < e; j0 += 4) {
        int j = j0 + slot;
        float w = 0.f; int s = 0;
        if (j < e) { s = csr_src[j]; w = wT[j]; }
        ushort4 f = *(const ushort4*)(h2 + (size_t)s * 64 + cg * 4);
        acc.x += w * bfu(f.x); acc.y += w * bfu(f.y);
        acc.z += w * bfu(f.z); acc.w += w * bfu(f.w);
    }
    acc.x += __shfl_xor(acc.x, 16, 64); acc.y += __shfl_xor(acc.y, 16, 64);
    acc.z += __shfl_xor(acc.z, 16, 64); acc.w += __shfl_xor(acc.w, 16, 64);
    acc.x += __shfl_xor(acc.x, 32, 64); acc.y += __shfl_xor(acc.y, 32, 64);
    acc.z += __shfl_xor(acc.z, 32, 64); acc.w += __shfl_xor(acc.w, 32, 64);
    float il = inv_l[n];
    float4 bb = *(const float4*)(bias + cg * 4);
    float4 v;
    v.x = acc.x * il + bb.x; v.y = acc.y * il + bb.y;
    v.z = acc.z * il + bb.z; v.w = acc.w * il + bb.w;
    v.x = (v.x > 0.f) ? v.x : expm1f(v.x);
    v.y = (v.y > 0.f) ? v.y : expm1f(v.y);
    v.z = (v.z > 0.f) ? v.z : expm1f(v.z);
    v.w = (v.w > 0.f) ? v.w : expm1f(v.w);
    int c0 = cg * 4;
    float o0 = v.x * Wout[(c0+0)*OUT_DIM+0] + v.y * Wout[(c0+1)*OUT_DIM+0]
             + v.z * Wout[(c0+2)*OUT_DIM+0] + v.w * Wout[(c0+3)*OUT_DIM+0];
    float o1 = v.x * Wout[(c0+0)*OUT_DIM+1] + v.y * Wout[(c0+1)*OUT_DIM+1]
             + v.z * Wout[(c0+2)*OUT_DIM+1] + v.w * Wout[(c0+3)*OUT_DIM+1];
    float o2 = v.x * Wout[(c0+0)*OUT_DIM+2] + v.y * Wout[(c0+1)*OUT_DIM+2]
             + v.z * Wout[(c0+2)*OUT_DIM+2] + v.w * Wout[(c0+3)*OUT_DIM+2];
    #pragma unroll
    for (int off = 1; off < 16; off <<= 1) {
        o0 += __shfl_xor(o0, off, 64);
        o1 += __shfl_xor(o1, off, 64);
        o2 += __shfl_xor(o2, off, 64);
    }
    if (lane == 0) {
        out[n * OUT_DIM + 0] = o0 + bout[0];
        out[n * OUT_DIM + 1] = o1 + bout[1];
        out[n * OUT_DIM + 2] = o2 + bout[2];
    }
}

extern "C" void kernel_launch(void* const* d_in, const int* in_sizes, int n_in,
                              void* d_out, int out_size, void* d_ws, size_t ws_size,
                              hipStream_t stream) {
    const float* x    = (const float*)d_in[0];
    const int*   ei   = (const int*)d_in[1];
    const float* W1   = (const float*)d_in[2];
    const float* as1  = (const float*)d_in[3];
    const float* ad1  = (const float*)d_in[4];
    const float* b1   = (const float*)d_in[5];
    const float* W2   = (const float*)d_in[6];
    const float* as2  = (const float*)d_in[7];
    const float* ad2  = (const float*)d_in[8];
    const float* b2v  = (const float*)d_in[9];
    const float* Wout = (const float*)d_in[10];
    const float* bout = (const float*)d_in[11];
    float* out = (float*)d_out;

    // ---- workspace layout (~70 MB), flag at base ----
    float* ws    = (float*)d_ws;
    int*   flag  = (int*)ws;                          // 16 floats reserved
    float* asb4  = ws + 16;                           // [N,4]
    float* adb4  = asb4 + (size_t)N_NODES * 4;        // [N,4]
    float* ilb4  = adb4 + (size_t)N_NODES * 4;        // [N,4]
    float* asb1  = ilb4 + (size_t)N_NODES * 4;        // [N]
    float* adb1  = asb1 + N_NODES;                    // [N]
    float* ilb1  = adb1 + N_NODES;                    // [N]
    float* wT    = ilb1 + N_NODES;                    // [4,E]
    __hip_bfloat16* h1     = (__hip_bfloat16*)(wT + (size_t)E_TOT * 4);       // [N,256] bf16
    __hip_bfloat16* eluagg = (__hip_bfloat16*)(h1 + (size_t)N_NODES * 256);   // [N,256] bf16
    __hip_bfloat16* h2     = (__hip_bfloat16*)(eluagg + (size_t)N_NODES * 256); // [N,64] bf16
    __hip_bfloat16* W1T    = (__hip_bfloat16*)(h2 + (size_t)N_NODES * 64);    // [256,128] bf16
    __hip_bfloat16* W2T    = W1T + 256 * 128;                                  // [64,256] bf16
    int* deg     = (int*)(W2T + 64 * 256);            // [N]
    int* bsums   = deg + N_NODES;                     // 64
    int* row_ptr = bsums + 64;                        // [N+1] (+pad)
    int* cursor  = row_ptr + N_NODES + 16;            // [N]
    int* csr_src = cursor + N_NODES;                  // [E]

    const int EB = (E_TOT + 255) / 256;
    const int NB = (N_NODES + 255) / 256;
    const int AB = (N_NODES + 3) / 4;
    const int MB = N_NODES / 16;                      // 3125 MFMA row-blocks

    detect_int64_kernel<<<1, 256, 0, stream>>>(ei, flag);
    hipMemsetAsync(deg, 0, (size_t)N_NODES * sizeof(int), stream);

    // ---- fused weight-prep + degree count; then scan chain; then scatter ----
    wprep_count_kernel<<<WPREP_BLOCKS + EB, 256, 0, stream>>>(W1, W1T, W2, W2T, ei, flag, deg);
    scan_local_kernel<<<N_CHUNKS, SCAN_CHUNK, 0, stream>>>(deg, row_ptr, bsums);
    scan_bsums_kernel<<<1, 64, 0, stream>>>(bsums);
    scan_add_kernel<<<NB, 256, 0, stream>>>(row_ptr, bsums, deg, cursor);
    scatter_kernel<<<EB, 256, 0, stream>>>(ei, flag, cursor, csr_src);

    // ===== layer 1: MFMA GEMM (+attn fused) + stats + gather(+bias+elu -> bf16) =====
    gemm_l1_mfma_kernel<<<MB, 256, 0, stream>>>(x, W1T, as1, ad1, h1, asb4, adb4);
    softmax_stats4_kernel<<<NB, 256, 0, stream>>>(row_ptr, csr_src, asb4, adb4, wT, ilb4);
    gat_gather4_kernel<<<AB, 256, 0, stream>>>(row_ptr, csr_src, wT, ilb4, h1, b1, eluagg);

    // ===== layer 2: MFMA GEMM (+attn fused) + stats =====
    gemm_l2_mfma_kernel<<<MB, 256, 0, stream>>>(eluagg, W2T, as2, ad2, h2, asb1, adb1);
    softmax_stats1_kernel<<<NB, 256, 0, stream>>>(row_ptr, csr_src, asb1, adb1, wT, ilb1);

    // ===== fused gather + elu + output projection =====
    gat_gather1_out_kernel<<<AB, 256, 0, stream>>>(row_ptr, csr_src, wT, ilb1, h2,
                                                   b2v, Wout, bout, out);
}

// Round 18
// 286.266 us; speedup vs baseline: 1.0756x; 1.0362x over previous
//
#include <hip/hip_runtime.h>
#include <hip/hip_bf16.h>
#include <math.h>

#define N_NODES  50000
#define IN_DIM   128
#define HIDDEN   64
#define OUT_DIM  3
#define HEADS1   4
#define E_RAW    400000
#define E_TOT    450000   // raw edges + one self loop per node
#define NEG_SLOPE 0.2f
#define SCAN_CHUNK 1024
#define N_CHUNKS ((N_NODES + SCAN_CHUNK - 1) / SCAN_CHUNK)   // 49
#define WPREP_BLOCKS 128

typedef __attribute__((ext_vector_type(8))) short bf16x8;
typedef __attribute__((ext_vector_type(4))) float f32x4;

// bf16 bits <-> float helpers (RN pack, shift-based unpack)
static __device__ __forceinline__ float bfu(unsigned short u) {
    return __uint_as_float(((unsigned)u) << 16);
}
static __device__ __forceinline__ unsigned short f2b_bits(float v) {
    __hip_bfloat16 b = __float2bfloat16(v);
    return *reinterpret_cast<unsigned short*>(&b);
}

// ---- edge fetch, robust to int32 vs int64 storage, indices clamped ----
static __device__ __forceinline__ void get_edge(const int* __restrict__ ei, int is64,
                                                int e, int& s, int& d) {
    if (e >= E_RAW) { s = d = e - E_RAW; return; }   // self loop
    if (is64) { s = ei[2 * e]; d = ei[2 * E_RAW + 2 * e]; }
    else      { s = ei[e];     d = ei[E_RAW + e]; }
    s = min(max(s, 0), N_NODES - 1);
    d = min(max(d, 0), N_NODES - 1);
}

// Detect int64 storage: high words of int64 pairs are all 0 for values < 2^31.
__global__ void detect_int64_kernel(const int* __restrict__ ei, int* __restrict__ flag) {
    __shared__ int any_nonzero;
    if (threadIdx.x == 0) any_nonzero = 0;
    __syncthreads();
    for (int i = threadIdx.x; i < 8192; i += blockDim.x) {
        int k = i * 48;                    // 2k+1 < 786,433: in-bounds for both layouts
        if (ei[2 * k + 1] != 0) any_nonzero = 1;   // benign race
    }
    __syncthreads();
    if (threadIdx.x == 0) flag[0] = (any_nonzero == 0) ? 1 : 0;
}

// ================= fused: weight prep (blocks 0..127) + degree count (rest) =================
__global__ void wprep_count_kernel(const float* __restrict__ W1, __hip_bfloat16* __restrict__ W1T,
                                   const float* __restrict__ W2, __hip_bfloat16* __restrict__ W2T,
                                   const int* __restrict__ ei, const int* __restrict__ flag,
                                   int* __restrict__ deg) {
    int bid = blockIdx.x;
    if (bid < WPREP_BLOCKS) {
        int i = bid * 256 + threadIdx.x;       // covers 32768 = 256*128
        if (i < 256 * 128) {
            int n = i >> 7, k = i & 127;
            *((unsigned short*)W1T + i) = f2b_bits(W1[k * 256 + n]);
        }
        if (i < 64 * 256) {
            int n = i >> 8, k = i & 255;
            *((unsigned short*)W2T + i) = f2b_bits(W2[k * 64 + n]);
        }
        return;
    }
    int e = (bid - WPREP_BLOCKS) * 256 + threadIdx.x;
    if (e >= E_TOT) return;
    int s, d;
    get_edge(ei, flag[0], e, s, d);
    atomicAdd(&deg[d], 1);
}

__global__ void scan_local_kernel(const int* __restrict__ deg, int* __restrict__ row_ptr,
                                  int* __restrict__ bsums) {
    __shared__ int buf[SCAN_CHUNK];
    int base = blockIdx.x * SCAN_CHUNK;
    int i = base + threadIdx.x;
    buf[threadIdx.x] = (i < N_NODES) ? deg[i] : 0;
    __syncthreads();
    for (int off = 1; off < SCAN_CHUNK; off <<= 1) {
        int t = (threadIdx.x >= off) ? buf[threadIdx.x - off] : 0;
        __syncthreads();
        buf[threadIdx.x] += t;
        __syncthreads();
    }
    if (i < N_NODES) row_ptr[i + 1] = buf[threadIdx.x];
    if (threadIdx.x == SCAN_CHUNK - 1) bsums[blockIdx.x] = buf[SCAN_CHUNK - 1];
    if (blockIdx.x == 0 && threadIdx.x == 0) row_ptr[0] = 0;
}

__global__ void scan_bsums_kernel(int* __restrict__ bsums) {
    __shared__ int buf[64];
    int i = threadIdx.x;
    buf[i] = (i < N_CHUNKS) ? bsums[i] : 0;
    __syncthreads();
    for (int off = 1; off < 64; off <<= 1) {
        int t = (i >= off) ? buf[i - off] : 0;
        __syncthreads();
        buf[i] += t;
        __syncthreads();
    }
    if (i < N_CHUNKS) bsums[i] = (i == 0) ? 0 : buf[i - 1];
}

__global__ void scan_add_kernel(int* __restrict__ row_ptr, const int* __restrict__ bsums,
                                const int* __restrict__ deg, int* __restrict__ cursor) {
    int i = blockIdx.x * blockDim.x + threadIdx.x;
    if (i < N_NODES) {
        int incl = row_ptr[i + 1] + bsums[i / SCAN_CHUNK];
        row_ptr[i + 1] = incl;
        cursor[i] = incl - deg[i];
    }
}

__global__ void scatter_kernel(const int* __restrict__ ei, const int* __restrict__ flag,
                               int* __restrict__ cursor, int* __restrict__ csr_src) {
    int e = blockIdx.x * blockDim.x + threadIdx.x;
    if (e >= E_TOT) return;
    int s, d;
    get_edge(ei, flag[0], e, s, d);
    int pos = atomicAdd(&cursor[d], 1);
    csr_src[pos] = s;
}

// ========== layer-1 GEMM via MFMA + fused attn scores ==========
__global__ void __launch_bounds__(256) gemm_l1_mfma_kernel(
        const float* __restrict__ x, const __hip_bfloat16* __restrict__ W1T,
        const float* __restrict__ att_s, const float* __restrict__ att_d,
        __hip_bfloat16* __restrict__ h1,
        float* __restrict__ asb4, float* __restrict__ adb4) {
    __shared__ unsigned short As[16][136];
    const int tid = threadIdx.x;
    const int wave = tid >> 6, lane = tid & 63;
    const int quad = lane >> 4, m = lane & 15;
    const int row0 = blockIdx.x * 16;        // 50000/16 = 3125 exact
    {
        int r = tid >> 4, seg = tid & 15;
        const float* xa = x + (size_t)(row0 + r) * IN_DIM + seg * 8;
        float4 u = *(const float4*)xa;
        float4 v = *(const float4*)(xa + 4);
        ushort4 p0, p1;
        p0.x = f2b_bits(u.x); p0.y = f2b_bits(u.y); p0.z = f2b_bits(u.z); p0.w = f2b_bits(u.w);
        p1.x = f2b_bits(v.x); p1.y = f2b_bits(v.y); p1.z = f2b_bits(v.z); p1.w = f2b_bits(v.w);
        *(ushort4*)&As[r][seg * 8]     = p0;
        *(ushort4*)&As[r][seg * 8 + 4] = p1;
    }
    __syncthreads();
    const int n0w = wave * 64;
    f32x4 acc0 = {0.f, 0.f, 0.f, 0.f}, acc1 = acc0, acc2 = acc0, acc3 = acc0;
    #pragma unroll
    for (int k0 = 0; k0 < IN_DIM; k0 += 32) {
        int kk = k0 + quad * 8;
        bf16x8 a = *(const bf16x8*)&As[m][kk];
        bf16x8 b0 = *(const bf16x8*)(W1T + (size_t)(n0w +  0 + m) * IN_DIM + kk);
        bf16x8 b1 = *(const bf16x8*)(W1T + (size_t)(n0w + 16 + m) * IN_DIM + kk);
        bf16x8 b2 = *(const bf16x8*)(W1T + (size_t)(n0w + 32 + m) * IN_DIM + kk);
        bf16x8 b3 = *(const bf16x8*)(W1T + (size_t)(n0w + 48 + m) * IN_DIM + kk);
        acc0 = __builtin_amdgcn_mfma_f32_16x16x32_bf16(a, b0, acc0, 0, 0, 0);
        acc1 = __builtin_amdgcn_mfma_f32_16x16x32_bf16(a, b1, acc1, 0, 0, 0);
        acc2 = __builtin_amdgcn_mfma_f32_16x16x32_bf16(a, b2, acc2, 0, 0, 0);
        acc3 = __builtin_amdgcn_mfma_f32_16x16x32_bf16(a, b3, acc3, 0, 0, 0);
    }
    float ats0 = att_s[n0w +  0 + m], atd0 = att_d[n0w +  0 + m];
    float ats1 = att_s[n0w + 16 + m], atd1 = att_d[n0w + 16 + m];
    float ats2 = att_s[n0w + 32 + m], atd2 = att_d[n0w + 32 + m];
    float ats3 = att_s[n0w + 48 + m], atd3 = att_d[n0w + 48 + m];
    unsigned short* out = (unsigned short*)h1;
    #pragma unroll
    for (int i = 0; i < 4; i++) {
        int grow = row0 + quad * 4 + i;
        size_t base = (size_t)grow * 256;
        out[base + n0w +  0 + m] = f2b_bits(acc0[i]);
        out[base + n0w + 16 + m] = f2b_bits(acc1[i]);
        out[base + n0w + 32 + m] = f2b_bits(acc2[i]);
        out[base + n0w + 48 + m] = f2b_bits(acc3[i]);
        float ps = acc0[i] * ats0 + acc1[i] * ats1 + acc2[i] * ats2 + acc3[i] * ats3;
        float pd = acc0[i] * atd0 + acc1[i] * atd1 + acc2[i] * atd2 + acc3[i] * atd3;
        #pragma unroll
        for (int off = 1; off < 16; off <<= 1) {
            ps += __shfl_xor(ps, off, 16);
            pd += __shfl_xor(pd, off, 16);
        }
        if (m == 0) {
            asb4[grow * 4 + wave] = ps;
            adb4[grow * 4 + wave] = pd;
        }
    }
}

// ========== layer-2 GEMM via MFMA + fused single-head attn scores ==========
__global__ void __launch_bounds__(256) gemm_l2_mfma_kernel(
        const __hip_bfloat16* __restrict__ eluagg, const __hip_bfloat16* __restrict__ W2T,
        const float* __restrict__ att_s, const float* __restrict__ att_d,
        __hip_bfloat16* __restrict__ h2,
        float* __restrict__ asb, float* __restrict__ adb) {
    __shared__ float sPS[4][16];
    __shared__ float sPD[4][16];
    const int tid = threadIdx.x;
    const int wave = tid >> 6, lane = tid & 63;
    const int quad = lane >> 4, m = lane & 15;
    const int row0 = blockIdx.x * 16;
    const int n0 = wave * 16;
    f32x4 acc = {0.f, 0.f, 0.f, 0.f};
    #pragma unroll
    for (int k0 = 0; k0 < 256; k0 += 32) {
        int kk = k0 + quad * 8;
        bf16x8 a = *(const bf16x8*)(eluagg + (size_t)(row0 + m) * 256 + kk);
        bf16x8 b = *(const bf16x8*)(W2T + (size_t)(n0 + m) * 256 + kk);
        acc = __builtin_amdgcn_mfma_f32_16x16x32_bf16(a, b, acc, 0, 0, 0);
    }
    float ats = att_s[n0 + m], atd = att_d[n0 + m];
    unsigned short* out = (unsigned short*)h2;
    #pragma unroll
    for (int i = 0; i < 4; i++) {
        int grow = row0 + quad * 4 + i;
        out[(size_t)grow * 64 + n0 + m] = f2b_bits(acc[i]);
        float ps = acc[i] * ats;
        float pd = acc[i] * atd;
        #pragma unroll
        for (int off = 1; off < 16; off <<= 1) {
            ps += __shfl_xor(ps, off, 16);
            pd += __shfl_xor(pd, off, 16);
        }
        if (m == 0) {
            sPS[wave][quad * 4 + i] = ps;
            sPD[wave][quad * 4 + i] = pd;
        }
    }
    __syncthreads();
    if (tid < 16) {
        float ps = sPS[0][tid] + sPS[1][tid] + sPS[2][tid] + sPS[3][tid];
        float pd = sPD[0][tid] + sPD[1][tid] + sPD[2][tid] + sPD[3][tid];
        asb[row0 + tid] = ps;
        adb[row0 + tid] = pd;
    }
}

// ========== gather4 with INLINE softmax + bias + elu -> bf16 eluagg [N,256] ==========
// per-edge weight computed in-register: w = exp(leaky(asb4[s][head] + adb4[n][head]))
// (single-pass softmax, shift-invariant; scores O(10) so exp can't overflow)
__global__ void __launch_bounds__(256) gat_gather4_kernel(
        const int* __restrict__ row_ptr, const int* __restrict__ csr_src,
        const float* __restrict__ asb4, const float* __restrict__ adb4,
        const __hip_bfloat16* __restrict__ h1, const float* __restrict__ bias,
        __hip_bfloat16* __restrict__ eluagg) {
    int wave = threadIdx.x >> 6;
    int lane = threadIdx.x & 63;
    int n = blockIdx.x * 4 + wave;
    if (n >= N_NODES) return;
    int b = row_ptr[n], e = row_ptr[n + 1];
    int head = lane >> 4;
    float adn = adb4[n * 4 + head];
    float4 a0 = make_float4(0, 0, 0, 0), a1 = a0, a2 = a0, a3 = a0;
    float l0 = 0.f, l1 = 0.f, l2 = 0.f, l3 = 0.f;
    int j = b;
    for (; j + 4 <= e; j += 4) {
        int s0 = csr_src[j], s1 = csr_src[j + 1], s2 = csr_src[j + 2], s3 = csr_src[j + 3];
        float v0 = asb4[s0 * 4 + head] + adn;
        float v1 = asb4[s1 * 4 + head] + adn;
        float v2 = asb4[s2 * 4 + head] + adn;
        float v3 = asb4[s3 * 4 + head] + adn;
        v0 = (v0 > 0.f) ? v0 : NEG_SLOPE * v0;
        v1 = (v1 > 0.f) ? v1 : NEG_SLOPE * v1;
        v2 = (v2 > 0.f) ? v2 : NEG_SLOPE * v2;
        v3 = (v3 > 0.f) ? v3 : NEG_SLOPE * v3;
        float w0 = __expf(v0), w1 = __expf(v1), w2 = __expf(v2), w3 = __expf(v3);
        ushort4 f0 = *(const ushort4*)(h1 + (size_t)s0 * 256 + lane * 4);
        ushort4 f1 = *(const ushort4*)(h1 + (size_t)s1 * 256 + lane * 4);
        ushort4 f2 = *(const ushort4*)(h1 + (size_t)s2 * 256 + lane * 4);
        ushort4 f3 = *(const ushort4*)(h1 + (size_t)s3 * 256 + lane * 4);
        l0 += w0; l1 += w1; l2 += w2; l3 += w3;
        a0.x += w0 * bfu(f0.x); a0.y += w0 * bfu(f0.y); a0.z += w0 * bfu(f0.z); a0.w += w0 * bfu(f0.w);
        a1.x += w1 * bfu(f1.x); a1.y += w1 * bfu(f1.y); a1.z += w1 * bfu(f1.z); a1.w += w1 * bfu(f1.w);
        a2.x += w2 * bfu(f2.x); a2.y += w2 * bfu(f2.y); a2.z += w2 * bfu(f2.z); a2.w += w2 * bfu(f2.w);
        a3.x += w3 * bfu(f3.x); a3.y += w3 * bfu(f3.y); a3.z += w3 * bfu(f3.z); a3.w += w3 * bfu(f3.w);
    }
    for (; j < e; j++) {
        int s = csr_src[j];
        float v = asb4[s * 4 + head] + adn;
        v = (v > 0.f) ? v : NEG_SLOPE * v;
        float w = __expf(v);
        ushort4 f = *(const ushort4*)(h1 + (size_t)s * 256 + lane * 4);
        l0 += w;
        a0.x += w * bfu(f.x); a0.y += w * bfu(f.y); a0.z += w * bfu(f.z); a0.w += w * bfu(f.w);
    }
    float il = 1.f / ((l0 + l1) + (l2 + l3) + 1e-16f);
    float4 bb = *(const float4*)(bias + lane * 4);
    float4 r;
    r.x = (a0.x + a1.x + a2.x + a3.x) * il + bb.x;
    r.y = (a0.y + a1.y + a2.y + a3.y) * il + bb.y;
    r.z = (a0.z + a1.z + a2.z + a3.z) * il + bb.z;
    r.w = (a0.w + a1.w + a2.w + a3.w) * il + bb.w;
    r.x = (r.x > 0.f) ? r.x : expm1f(r.x);
    r.y = (r.y > 0.f) ? r.y : expm1f(r.y);
    r.z = (r.z > 0.f) ? r.z : expm1f(r.z);
    r.w = (r.w > 0.f) ? r.w : expm1f(r.w);
    ushort4 st;
    st.x = f2b_bits(r.x); st.y = f2b_bits(r.y); st.z = f2b_bits(r.z); st.w = f2b_bits(r.w);
    *(ushort4*)(eluagg + (size_t)n * 256 + lane * 4) = st;
}

// ========== gather1 with INLINE softmax + elu + output projection ==========
__global__ void __launch_bounds__(256) gat_gather1_out_kernel(
        const int* __restrict__ row_ptr, const int* __restrict__ csr_src,
        const float* __restrict__ asb, const float* __restrict__ adb,
        const __hip_bfloat16* __restrict__ h2, const float* __restrict__ bias,
        const float* __restrict__ Wout, const float* __restrict__ bout,
        float* __restrict__ out) {
    int wave = threadIdx.x >> 6;
    int lane = threadIdx.x & 63;
    int n = blockIdx.x * 4 + wave;
    if (n >= N_NODES) return;
    int b = row_ptr[n], e = row_ptr[n + 1];
    int cg = lane & 15, slot = lane >> 4;
    float adn = adb[n];
    float4 acc = make_float4(0, 0, 0, 0);
    float l = 0.f;
    for (int j0 = b; j0 < e; j0 += 4) {
        int j = j0 + slot;
        float w = 0.f; int s = 0;
        if (j < e) {
            s = csr_src[j];
            float v = asb[s] + adn;
            v = (v > 0.f) ? v : NEG_SLOPE * v;
            w = __expf(v);
        }
        ushort4 f = *(const ushort4*)(h2 + (size_t)s * 64 + cg * 4);
        l += w;
        acc.x += w * bfu(f.x); acc.y += w * bfu(f.y);
        acc.z += w * bfu(f.z); acc.w += w * bfu(f.w);
    }
    acc.x += __shfl_xor(acc.x, 16, 64); acc.y += __shfl_xor(acc.y, 16, 64);
    acc.z += __shfl_xor(acc.z, 16, 64); acc.w += __shfl_xor(acc.w, 16, 64);
    l += __shfl_xor(l, 16, 64);
    acc.x += __shfl_xor(acc.x, 32, 64); acc.y += __shfl_xor(acc.y, 32, 64);
    acc.z += __shfl_xor(acc.z, 32, 64); acc.w += __shfl_xor(acc.w, 32, 64);
    l += __shfl_xor(l, 32, 64);
    float il = 1.f / (l + 1e-16f);
    float4 bb = *(const float4*)(bias + cg * 4);
    float4 v;
    v.x = acc.x * il + bb.x; v.y = acc.y * il + bb.y;
    v.z = acc.z * il + bb.z; v.w = acc.w * il + bb.w;
    v.x = (v.x > 0.f) ? v.x : expm1f(v.x);
    v.y = (v.y > 0.f) ? v.y : expm1f(v.y);
    v.z = (v.z > 0.f) ? v.z : expm1f(v.z);
    v.w = (v.w > 0.f) ? v.w : expm1f(v.w);
    int c0 = cg * 4;
    float o0 = v.x * Wout[(c0+0)*OUT_DIM+0] + v.y * Wout[(c0+1)*OUT_DIM+0]
             + v.z * Wout[(c0+2)*OUT_DIM+0] + v.w * Wout[(c0+3)*OUT_DIM+0];
    float o1 = v.x * Wout[(c0+0)*OUT_DIM+1] + v.y * Wout[(c0+1)*OUT_DIM+1]
             + v.z * Wout[(c0+2)*OUT_DIM+1] + v.w * Wout[(c0+3)*OUT_DIM+1];
    float o2 = v.x * Wout[(c0+0)*OUT_DIM+2] + v.y * Wout[(c0+1)*OUT_DIM+2]
             + v.z * Wout[(c0+2)*OUT_DIM+2] + v.w * Wout[(c0+3)*OUT_DIM+2];
    #pragma unroll
    for (int off = 1; off < 16; off <<= 1) {
        o0 += __shfl_xor(o0, off, 64);
        o1 += __shfl_xor(o1, off, 64);
        o2 += __shfl_xor(o2, off, 64);
    }
    if (lane == 0) {
        out[n * OUT_DIM + 0] = o0 + bout[0];
        out[n * OUT_DIM + 1] = o1 + bout[1];
        out[n * OUT_DIM + 2] = o2 + bout[2];
    }
}

extern "C" void kernel_launch(void* const* d_in, const int* in_sizes, int n_in,
                              void* d_out, int out_size, void* d_ws, size_t ws_size,
                              hipStream_t stream) {
    const float* x    = (const float*)d_in[0];
    const int*   ei   = (const int*)d_in[1];
    const float* W1   = (const float*)d_in[2];
    const float* as1  = (const float*)d_in[3];
    const float* ad1  = (const float*)d_in[4];
    const float* b1   = (const float*)d_in[5];
    const float* W2   = (const float*)d_in[6];
    const float* as2  = (const float*)d_in[7];
    const float* ad2  = (const float*)d_in[8];
    const float* b2v  = (const float*)d_in[9];
    const float* Wout = (const float*)d_in[10];
    const float* bout = (const float*)d_in[11];
    float* out = (float*)d_out;

    // ---- workspace layout (~60 MB), flag at base ----
    float* ws    = (float*)d_ws;
    int*   flag  = (int*)ws;                          // 16 floats reserved
    float* asb4  = ws + 16;                           // [N,4]
    float* adb4  = asb4 + (size_t)N_NODES * 4;        // [N,4]
    float* asb1  = adb4 + (size_t)N_NODES * 4;        // [N]
    float* adb1  = asb1 + N_NODES;                    // [N]
    __hip_bfloat16* h1     = (__hip_bfloat16*)(adb1 + N_NODES);               // [N,256] bf16
    __hip_bfloat16* eluagg = (__hip_bfloat16*)(h1 + (size_t)N_NODES * 256);   // [N,256] bf16
    __hip_bfloat16* h2     = (__hip_bfloat16*)(eluagg + (size_t)N_NODES * 256); // [N,64] bf16
    __hip_bfloat16* W1T    = (__hip_bfloat16*)(h2 + (size_t)N_NODES * 64);    // [256,128] bf16
    __hip_bfloat16* W2T    = W1T + 256 * 128;                                  // [64,256] bf16
    int* deg     = (int*)(W2T + 64 * 256);            // [N]
    int* bsums   = deg + N_NODES;                     // 64
    int* row_ptr = bsums + 64;                        // [N+1] (+pad)
    int* cursor  = row_ptr + N_NODES + 16;            // [N]
    int* csr_src = cursor + N_NODES;                  // [E]

    const int EB = (E_TOT + 255) / 256;
    const int NB = (N_NODES + 255) / 256;
    const int AB = (N_NODES + 3) / 4;
    const int MB = N_NODES / 16;                      // 3125 MFMA row-blocks

    detect_int64_kernel<<<1, 256, 0, stream>>>(ei, flag);
    hipMemsetAsync(deg, 0, (size_t)N_NODES * sizeof(int), stream);

    // ---- fused weight-prep + degree count; scan chain; scatter ----
    wprep_count_kernel<<<WPREP_BLOCKS + EB, 256, 0, stream>>>(W1, W1T, W2, W2T, ei, flag, deg);
    scan_local_kernel<<<N_CHUNKS, SCAN_CHUNK, 0, stream>>>(deg, row_ptr, bsums);
    scan_bsums_kernel<<<1, 64, 0, stream>>>(bsums);
    scan_add_kernel<<<NB, 256, 0, stream>>>(row_ptr, bsums, deg, cursor);
    scatter_kernel<<<EB, 256, 0, stream>>>(ei, flag, cursor, csr_src);

    // ===== layer 1: MFMA GEMM (+attn fused) + gather (inline softmax, +bias+elu) =====
    gemm_l1_mfma_kernel<<<MB, 256, 0, stream>>>(x, W1T, as1, ad1, h1, asb4, adb4);
    gat_gather4_kernel<<<AB, 256, 0, stream>>>(row_ptr, csr_src, asb4, adb4, h1, b1, eluagg);

    // ===== layer 2: MFMA GEMM (+attn fused) + gather (inline softmax) + out proj =====
    gemm_l2_mfma_kernel<<<MB, 256, 0, stream>>>(eluagg, W2T, as2, ad2, h2, asb1, adb1);
    gat_gather1_out_kernel<<<AB, 256, 0, stream>>>(row_ptr, csr_src, asb1, adb1, h2,
                                                   b2v, Wout, bout, out);
}